// Round 6
// baseline (86.495 us; speedup 1.0000x reference)
//
#include <hip/hip_runtime.h>
#include <hip/hip_bf16.h>

#define HH 200
#define WW 176
#define CIN 256
#define CO 28
#define BN_EPS 1e-3f

typedef __attribute__((ext_vector_type(8))) short short8;
typedef __attribute__((ext_vector_type(4))) float f32x4;

static __device__ __forceinline__ ushort f2bf(float f) {
    __hip_bfloat16 h = __float2bfloat16(f);
    return __builtin_bit_cast(ushort, h);
}

// ---------------------------------------------------------------------------
// prep: w1b chunk-major [h][t][n][lane][j] (bf16, BN-folded), plus shift[28].
//   co = n*16 + (lane&15), ci = h*32 + (lane>>4)*8 + j
// ---------------------------------------------------------------------------
__global__ void prep_k(const float* __restrict__ w1, const float* __restrict__ gamma,
                       const float* __restrict__ beta, const float* __restrict__ mean,
                       const float* __restrict__ var, ushort* __restrict__ w1b,
                       float* __restrict__ shift)
{
    int idx = blockIdx.x * 256 + threadIdx.x;
    if (idx < CO) {
        float sc = gamma[idx] * rsqrtf(var[idx] + BN_EPS);
        shift[idx] = beta[idx] - mean[idx] * sc;
    }
    if (idx < 8 * 9 * 2 * 64 * 8) {
        int j   = idx & 7;
        int l   = (idx >> 3) & 63;
        int n   = (idx >> 9) & 1;
        int rem = idx >> 10;          // h*9 + t
        int t   = rem % 9;
        int h   = rem / 9;
        int co = n * 16 + (l & 15);
        int ci = h * 32 + (l >> 4) * 8 + j;
        float v = 0.f;
        if (co < CO) {
            float sc = gamma[co] * rsqrtf(var[co] + BN_EPS);
            v = w1[(co * CIN + ci) * 9 + t] * sc;
        }
        w1b[idx] = f2bf(v);
    }
}

// ---------------------------------------------------------------------------
// Implicit-GEMM conv3x3 + BN + ReLU via bf16 MFMA.
// Tile 16x8 px, 4 waves; wave w owns rows {2w,2w+1}, stages ci-octet w.
// x halo 18x10 px x 32ci bf16, DOUBLE-buffered in LDS (16B-unit swizzle).
// Weights: global->VGPR per chunk (L2-hot, coalesced b128), no LDS round-trip.
// Per chunk, 3 sched-fenced phases, ONE barrier:
//   [issue w(h)+x(h+1)] | [12 ds_read A + 36 MFMA] | [cvt+ds_write x(h+1), bar]
// ---------------------------------------------------------------------------
__global__ __launch_bounds__(256, 3) void conv_mfma_k(
    const float* __restrict__ x, const ushort* __restrict__ w1b,
    const float* __restrict__ shift, float* __restrict__ y1)
{
    __shared__ uint4 sbuf[2][180 * 4];    // 2 x 11520 B (x halo dbuf)

    const int tid  = threadIdx.x;
    const int lane = tid & 63;
    const int w    = tid >> 6;            // wave id == ci octet

    // XCD-aware bijective block swizzle (1100 blocks, 8 XCDs)
    const int NB = 11 * 25 * 4;
    const int q = NB / 8, r = NB % 8;     // 137, 4
    const int bid  = blockIdx.x;
    const int xcd  = bid & 7;
    const int rank = bid >> 3;
    const int tile = (xcd < r ? xcd * (q + 1) : r * (q + 1) + (xcd - r) * q) + rank;

    const int tx  = tile % 11;
    const int rem = tile / 11;
    const int ty  = rem % 25;
    const int b   = rem / 25;
    const int x0  = tx * 16, y0 = ty * 8;

    const float* xb = x + (size_t)b * CIN * HH * WW;

    // chunk-invariant per-lane staging geometry (halo 18 wide x 10 tall)
    int  soff[3]; bool sval[3]; bool sp[3];
#pragma unroll
    for (int it = 0; it < 3; ++it) {
        int p = it * 64 + lane;
        sp[it] = p < 180;
        int rr = p / 18, cc = p - rr * 18;
        int gy = y0 + rr - 1, gx = x0 + cc - 1;
        bool v = (gy >= 0) & (gy < HH) & (gx >= 0) & (gx < WW) & sp[it];
        sval[it] = v;
        soff[it] = v ? gy * WW + gx : 0;
    }

    float pre[3][8];

    auto issue_x = [&](int h) {
        const float* pl = xb + (size_t)(h * 32 + w * 8) * (HH * WW);
#pragma unroll
        for (int it = 0; it < 3; ++it) {
            if (sp[it]) {
#pragma unroll
                for (int j = 0; j < 8; ++j)
                    pre[it][j] = pl[(size_t)j * (HH * WW) + soff[it]];
            }
        }
    };

    auto wr_x = [&](int bi) {
#pragma unroll
        for (int it = 0; it < 3; ++it) {
            if (sp[it]) {
                int p = it * 64 + lane;
                ushort u[8];
#pragma unroll
                for (int j = 0; j < 8; ++j)
                    u[j] = sval[it] ? f2bf(pre[it][j]) : (ushort)0;
                uint4 val;
                val.x = (uint)u[0] | ((uint)u[1] << 16);
                val.y = (uint)u[2] | ((uint)u[3] << 16);
                val.z = (uint)u[4] | ((uint)u[5] << 16);
                val.w = (uint)u[6] | ((uint)u[7] << 16);
                sbuf[bi][p * 4 + ((w + p) & 3)] = val;
            }
        }
    };

    f32x4 acc[2][2];
#pragma unroll
    for (int m = 0; m < 2; ++m)
#pragma unroll
        for (int n = 0; n < 2; ++n)
            acc[m][n] = (f32x4){0.f, 0.f, 0.f, 0.f};

    // prologue: stage x(0)
    issue_x(0);
    wr_x(0);
    __syncthreads();

#pragma unroll 1
    for (int h = 0; h < 8; ++h) {
        // ---- phase 1: issue all global loads (w first: consumed first)
        short8 wreg[9][2];
        {
            const ushort* wsrc = w1b + (size_t)h * 9216;
#pragma unroll
            for (int t = 0; t < 9; ++t)
#pragma unroll
                for (int n = 0; n < 2; ++n)
                    wreg[t][n] = *(const short8*)(wsrc + (size_t)((t * 2 + n) * 64 + lane) * 8);
        }
        if (h < 7) issue_x(h + 1);
        __builtin_amdgcn_sched_barrier(0);

        // ---- phase 2: 12 A-frag ds_reads + 36 MFMA
        {
            const uint4* sb = sbuf[h & 1];
            short8 av[4][3];
#pragma unroll
            for (int rr = 0; rr < 4; ++rr) {        // image row 2w-1+rr
#pragma unroll
                for (int dx = 0; dx < 3; ++dx) {
                    int p = (2 * w + rr) * 18 + (lane & 15) + dx;
                    av[rr][dx] = __builtin_bit_cast(short8, sb[p * 4 + (((lane >> 4) + p) & 3)]);
                }
            }
#pragma unroll
            for (int t = 0; t < 9; ++t) {
                const int dy = t / 3, dx = t % 3;
#pragma unroll
                for (int m = 0; m < 2; ++m) {
                    short8 af = av[m + dy][dx];
                    acc[m][0] = __builtin_amdgcn_mfma_f32_16x16x32_bf16(af, wreg[t][0], acc[m][0], 0, 0, 0);
                    acc[m][1] = __builtin_amdgcn_mfma_f32_16x16x32_bf16(af, wreg[t][1], acc[m][1], 0, 0, 0);
                }
            }
        }
        __builtin_amdgcn_sched_barrier(0);

        // ---- phase 3: stage x(h+1) into other buffer, single barrier
        if (h < 7) {
            wr_x((h + 1) & 1);
            __syncthreads();
        }
    }

    // epilogue: + shift, ReLU, store channel-last y1
    const int co0 = lane & 15;
    const int co1 = 16 + co0;
    const float s0 = shift[co0];
    const float s1 = (co1 < CO) ? shift[co1] : 0.f;
#pragma unroll
    for (int m = 0; m < 2; ++m) {
        int gy = y0 + 2 * w + m;
#pragma unroll
        for (int reg = 0; reg < 4; ++reg) {
            int gx = x0 + (lane >> 4) * 4 + reg;
            float* yp = y1 + ((size_t)(b * HH + gy) * WW + gx) * CO;
            float v0 = acc[m][0][reg] + s0;
            yp[co0] = v0 > 0.f ? v0 : 0.f;
            if (co1 < CO) {
                float v1 = acc[m][1][reg] + s1;
                yp[co1] = v1 > 0.f ? v1 : 0.f;
            }
        }
    }
}

// ---------------------------------------------------------------------------
// Sampler: thread = (box, k).  Bilinear sample of conv1x1 output = conv1x1 of
// bilinear samples (linear, bias-free).  Mean over k via LDS reduce.
// ---------------------------------------------------------------------------
__global__ __launch_bounds__(224) void sample_k(
    const float* __restrict__ y1, const float* __restrict__ ga,
    const float* __restrict__ w2, float* __restrict__ out)
{
    __shared__ float red[224];
    const int lb  = threadIdx.x / CO;   // local box 0..7
    const int k   = threadIdx.x % CO;   // window index / channel
    const int box = blockIdx.x * 8 + lb;
    const int b   = box >> 11;          // / 2048

    const float* ap = ga + (size_t)box * 7;
    float xg = ap[0], yg = ap[1], wg = ap[3], lg = ap[4], rg = ap[6];
    float c = cosf(rg), s = sinf(rg);

    const int i = k / 7, j = k % 7;
    float xx = ((float)i * (1.f / 3.f) - 0.5f) * wg;
    float yy = ((float)j * (1.f / 6.f) - 0.5f) * lg;
    float xs = (xx * c + yy * s + xg) * 2.5f;
    float ys = (yy * c - xx * s + yg + 40.f) * 2.5f;

    float x0 = floorf(xs), y0 = floorf(ys);
    float wx = xs - x0,    wy = ys - y0;

    float w2r[CO];
    const float* w2p = w2 + k * CO;
#pragma unroll
    for (int q = 0; q < 7; ++q) {
        float4 t = ((const float4*)w2p)[q];
        w2r[4*q] = t.x; w2r[4*q+1] = t.y; w2r[4*q+2] = t.z; w2r[4*q+3] = t.w;
    }

    float val = 0.f;
    const float* yb = y1 + (size_t)b * HH * WW * CO;
#pragma unroll
    for (int cor = 0; cor < 4; ++cor) {
        float yf = y0 + (float)(cor >> 1);
        float xf = x0 + (float)(cor & 1);
        float cw = ((cor & 1) ? wx : 1.f - wx) * ((cor >> 1) ? wy : 1.f - wy);
        if (yf >= 0.f && yf <= (float)(HH - 1) && xf >= 0.f && xf <= (float)(WW - 1)) {
            int yi = (int)yf, xi = (int)xf;
            const float* p = yb + ((size_t)yi * WW + xi) * CO;
            float d = 0.f;
#pragma unroll
            for (int q = 0; q < 7; ++q) {
                float4 t = ((const float4*)p)[q];
                d = fmaf(w2r[4*q],   t.x, d);
                d = fmaf(w2r[4*q+1], t.y, d);
                d = fmaf(w2r[4*q+2], t.z, d);
                d = fmaf(w2r[4*q+3], t.w, d);
            }
            val = fmaf(cw, d, val);
        }
    }

    red[threadIdx.x] = val;
    __syncthreads();
    if (k == 0) {
        float sum = 0.f;
#pragma unroll
        for (int q = 0; q < CO; ++q) sum += red[lb * CO + q];
        out[box] = sum * (1.f / 28.f);
    }
}

// ---------------------------------------------------------------------------
extern "C" void kernel_launch(void* const* d_in, const int* in_sizes, int n_in,
                              void* d_out, int out_size, void* d_ws, size_t ws_size,
                              hipStream_t stream) {
    const float* x     = (const float*)d_in[0];
    const float* ga    = (const float*)d_in[1];
    const float* w1    = (const float*)d_in[2];
    const float* gamma = (const float*)d_in[3];
    const float* beta  = (const float*)d_in[4];
    const float* mean  = (const float*)d_in[5];
    const float* var   = (const float*)d_in[6];
    const float* w2    = (const float*)d_in[7];
    float* out = (float*)d_out;

    ushort* w1b   = (ushort*)d_ws;                         // 147456 B
    float*  shift = (float*)((char*)d_ws + 147456);        // 112 B
    float*  y1    = (float*)((char*)d_ws + 147968);        // 4*200*176*28 f32

    prep_k<<<(8 * 9 * 2 * 64 * 8 + 255) / 256, 256, 0, stream>>>(
        w1, gamma, beta, mean, var, w1b, shift);

    conv_mfma_k<<<11 * 25 * 4, 256, 0, stream>>>(x, w1b, shift, y1);

    sample_k<<<(4 * 2048) / 8, 224, 0, stream>>>(y1, ga, w2, out);
}